// Round 1
// baseline (2843.321 us; speedup 1.0000x reference)
//
#include <hip/hip_runtime.h>

typedef float f4 __attribute__((ext_vector_type(4)));

#define T_SEQ 2048
#define NFEAT 512
#define NHEAD 8
#define DK    64
#define BATCH 4

// C[M,N] = A[M,K] @ W[N,K]^T + bias ; 64x64 tile, 16x16 threads, 4x4 per thread
__global__ __launch_bounds__(256) void gemm_bias(
    const float* __restrict__ A,
    const float* __restrict__ W,
    const float* __restrict__ bias,
    float* __restrict__ C,
    int M, int N, int K)
{
    __shared__ float As[16][64];   // [k][m]
    __shared__ float Ws[16][64];   // [k][n]
    const int tid = threadIdx.x;
    const int tx = tid & 15, ty = tid >> 4;
    const int row0 = blockIdx.y * 64, col0 = blockIdx.x * 64;
    const int lr = tid >> 2;            // 0..63
    const int lc = (tid & 3) * 4;       // 0,4,8,12

    float acc[4][4] = {};
    for (int k0 = 0; k0 < K; k0 += 16) {
        f4 a = *(const f4*)(A + (size_t)(row0 + lr) * K + k0 + lc);
        f4 w = *(const f4*)(W + (size_t)(col0 + lr) * K + k0 + lc);
#pragma unroll
        for (int i = 0; i < 4; ++i) As[lc + i][lr] = a[i];
#pragma unroll
        for (int i = 0; i < 4; ++i) Ws[lc + i][lr] = w[i];
        __syncthreads();
#pragma unroll
        for (int kk = 0; kk < 16; ++kk) {
            f4 av = *(const f4*)&As[kk][ty * 4];
            f4 wv = *(const f4*)&Ws[kk][tx * 4];
#pragma unroll
            for (int i = 0; i < 4; ++i)
#pragma unroll
                for (int j = 0; j < 4; ++j)
                    acc[i][j] += av[i] * wv[j];
        }
        __syncthreads();
    }
    float bv[4] = {0.f, 0.f, 0.f, 0.f};
    if (bias) {
#pragma unroll
        for (int j = 0; j < 4; ++j) bv[j] = bias[col0 + tx * 4 + j];
    }
#pragma unroll
    for (int i = 0; i < 4; ++i) {
        f4 o;
#pragma unroll
        for (int j = 0; j < 4; ++j) o[j] = acc[i][j] + bv[j];
        *(f4*)(C + (size_t)(row0 + ty * 4 + i) * N + col0 + tx * 4) = o;
    }
}

// c[b,h,s] = u[h]·k[b,h,s,:] + vb[h]·p[h,s,:]
__global__ __launch_bounds__(256) void cbias_kernel(
    const float* __restrict__ k, const float* __restrict__ p,
    const float* __restrict__ u, const float* __restrict__ vb,
    float* __restrict__ c)
{
    int idx = blockIdx.x * 256 + threadIdx.x;   // (b*H+h)*T + s
    int s  = idx & (T_SEQ - 1);
    int bh = idx >> 11;
    int b = bh >> 3, h = bh & 7;
    const float* kr = k + (size_t)(b * T_SEQ + s) * NFEAT + h * DK;
    const float* pr = p + (size_t)s * NFEAT + h * DK;
    const float* ur = u + h * DK;
    const float* vr = vb + h * DK;
    float acc = 0.f;
#pragma unroll 4
    for (int d = 0; d < DK; ++d) acc += ur[d] * kr[d] + vr[d] * pr[d];
    c[idx] = acc;
}

// Flash-style attention over KP = K + P with additive key bias c, scale 1/8.
// grid: (T/64, B*H); block 256. O written in [b][t][h*d] layout.
__global__ __launch_bounds__(256) void attn_kernel(
    const float* __restrict__ q, const float* __restrict__ k,
    const float* __restrict__ v, const float* __restrict__ p,
    const float* __restrict__ cbias, float* __restrict__ o)
{
    __shared__ float Qs[64][64];    // [t][d]
    __shared__ float KPs[64][64];   // [s][d]; reused as P[t][s] after scores
    __shared__ float Vts[64][64];   // [d][s] (transposed V)
    __shared__ float cs[64];
    const int tid = threadIdx.x;
    const int tx = tid & 15, ty = tid >> 4;
    const int bh = blockIdx.y, b = bh >> 3, h = bh & 7;
    const int t0 = blockIdx.x * 64;
    const int lr = tid >> 2;            // 0..63
    const int lc = (tid & 3) * 16;      // 0,16,32,48

    {
        const float* qp = q + (size_t)(b * T_SEQ + t0 + lr) * NFEAT + h * DK + lc;
#pragma unroll
        for (int i = 0; i < 16; i += 4)
            *(f4*)&Qs[lr][lc + i] = *(const f4*)(qp + i);
    }
    float m[4], l[4], accO[4][4] = {};
#pragma unroll
    for (int i = 0; i < 4; ++i) { m[i] = -1e30f; l[i] = 0.f; }

    for (int s0 = 0; s0 < T_SEQ; s0 += 64) {
        __syncthreads();   // prior-iter LDS reads complete (also fences Q load)
        const float* kr = k + (size_t)(b * T_SEQ + s0 + lr) * NFEAT + h * DK + lc;
        const float* pr = p + (size_t)(s0 + lr) * NFEAT + h * DK + lc;
        const float* vr = v + (size_t)(b * T_SEQ + s0 + lr) * NFEAT + h * DK + lc;
#pragma unroll
        for (int i = 0; i < 16; i += 4) {
            f4 kv = *(const f4*)(kr + i);
            f4 pv = *(const f4*)(pr + i);
            f4 kp = kv + pv;
            *(f4*)&KPs[lr][lc + i] = kp;
            f4 vv = *(const f4*)(vr + i);
            Vts[lc + i + 0][lr] = vv[0];
            Vts[lc + i + 1][lr] = vv[1];
            Vts[lc + i + 2][lr] = vv[2];
            Vts[lc + i + 3][lr] = vv[3];
        }
        if (tid < 64) cs[tid] = cbias[(size_t)bh * T_SEQ + s0 + tid];
        __syncthreads();

        // S[4][4] = Q @ KP^T for rows ty*4+i, cols tx*4+j
        float sa[4][4] = {};
#pragma unroll
        for (int d4 = 0; d4 < 16; ++d4) {
            f4 qa[4], kb[4];
#pragma unroll
            for (int i = 0; i < 4; ++i) qa[i] = *(const f4*)&Qs[ty * 4 + i][d4 * 4];
#pragma unroll
            for (int j = 0; j < 4; ++j) kb[j] = *(const f4*)&KPs[tx * 4 + j][d4 * 4];
#pragma unroll
            for (int i = 0; i < 4; ++i)
#pragma unroll
                for (int j = 0; j < 4; ++j)
                    sa[i][j] += qa[i][0] * kb[j][0] + qa[i][1] * kb[j][1]
                              + qa[i][2] * kb[j][2] + qa[i][3] * kb[j][3];
        }
#pragma unroll
        for (int i = 0; i < 4; ++i)
#pragma unroll
            for (int j = 0; j < 4; ++j)
                sa[i][j] = (sa[i][j] + cs[tx * 4 + j]) * 0.125f;

        // online softmax; rows owned by the 16-lane tx-group sharing ty
#pragma unroll
        for (int i = 0; i < 4; ++i) {
            float rm = fmaxf(fmaxf(sa[i][0], sa[i][1]), fmaxf(sa[i][2], sa[i][3]));
#pragma unroll
            for (int off = 1; off < 16; off <<= 1) rm = fmaxf(rm, __shfl_xor(rm, off));
            float mn = fmaxf(m[i], rm);
            float alpha = __expf(m[i] - mn);
            l[i] *= alpha;
#pragma unroll
            for (int j = 0; j < 4; ++j) accO[i][j] *= alpha;
            float rs = 0.f;
#pragma unroll
            for (int j = 0; j < 4; ++j) { sa[i][j] = __expf(sa[i][j] - mn); rs += sa[i][j]; }
#pragma unroll
            for (int off = 1; off < 16; off <<= 1) rs += __shfl_xor(rs, off);
            l[i] += rs;
            m[i] = mn;
        }
        __syncthreads();   // all KPs reads done before overwrite with P
#pragma unroll
        for (int i = 0; i < 4; ++i) {
            f4 pw;
#pragma unroll
            for (int j = 0; j < 4; ++j) pw[j] = sa[i][j];
            *(f4*)&KPs[ty * 4 + i][tx * 4] = pw;
        }
        __syncthreads();
        // O += P @ V  (P in KPs[t][s], V^T in Vts[d][s])
#pragma unroll
        for (int s4 = 0; s4 < 16; ++s4) {
            f4 pa[4], vb4[4];
#pragma unroll
            for (int i = 0; i < 4; ++i) pa[i] = *(const f4*)&KPs[ty * 4 + i][s4 * 4];
#pragma unroll
            for (int j = 0; j < 4; ++j) vb4[j] = *(const f4*)&Vts[tx * 4 + j][s4 * 4];
#pragma unroll
            for (int i = 0; i < 4; ++i)
#pragma unroll
                for (int j = 0; j < 4; ++j)
                    accO[i][j] += pa[i][0] * vb4[j][0] + pa[i][1] * vb4[j][1]
                                + pa[i][2] * vb4[j][2] + pa[i][3] * vb4[j][3];
        }
    }
#pragma unroll
    for (int i = 0; i < 4; ++i) {
        float inv = 1.f / l[i];
        f4 ov;
#pragma unroll
        for (int j = 0; j < 4; ++j) ov[j] = accO[i][j] * inv;
        *(f4*)(o + (size_t)(b * T_SEQ + t0 + ty * 4 + i) * NFEAT + h * DK + tx * 4) = ov;
    }
}

extern "C" void kernel_launch(void* const* d_in, const int* in_sizes, int n_in,
                              void* d_out, int out_size, void* d_ws, size_t ws_size,
                              hipStream_t stream)
{
    const float* x    = (const float*)d_in[0];
    const float* pos  = (const float*)d_in[1];
    const float* Wq   = (const float*)d_in[2];
    const float* bq   = (const float*)d_in[3];
    const float* Wk   = (const float*)d_in[4];
    const float* bk   = (const float*)d_in[5];
    const float* Wv   = (const float*)d_in[6];
    const float* bv   = (const float*)d_in[7];
    const float* Wpos = (const float*)d_in[8];
    const float* Wout = (const float*)d_in[9];
    const float* bout = (const float*)d_in[10];
    const float* pbu  = (const float*)d_in[11];
    const float* pbv  = (const float*)d_in[12];
    float* out = (float*)d_out;

    const int M = BATCH * T_SEQ;  // 8192
    float* ws   = (float*)d_ws;   // needs ~71.6 MB
    float* Q    = ws;
    float* Km   = Q   + (size_t)M * NFEAT;
    float* Vm   = Km  + (size_t)M * NFEAT;
    float* Pm   = Vm  + (size_t)M * NFEAT;
    float* Cb   = Pm  + (size_t)T_SEQ * NFEAT;
    float* AttO = Cb  + (size_t)BATCH * NHEAD * T_SEQ;

    dim3 blk(256);
    gemm_bias<<<dim3(NFEAT / 64, M / 64),     blk, 0, stream>>>(x,    Wq,   bq,      Q,    M,     NFEAT, NFEAT);
    gemm_bias<<<dim3(NFEAT / 64, M / 64),     blk, 0, stream>>>(x,    Wk,   bk,      Km,   M,     NFEAT, NFEAT);
    gemm_bias<<<dim3(NFEAT / 64, M / 64),     blk, 0, stream>>>(x,    Wv,   bv,      Vm,   M,     NFEAT, NFEAT);
    gemm_bias<<<dim3(NFEAT / 64, T_SEQ / 64), blk, 0, stream>>>(pos,  Wpos, nullptr, Pm,   T_SEQ, NFEAT, NFEAT);
    cbias_kernel<<<dim3(BATCH * NHEAD * T_SEQ / 256), blk, 0, stream>>>(Km, Pm, pbu, pbv, Cb);
    attn_kernel<<<dim3(T_SEQ / 64, BATCH * NHEAD), blk, 0, stream>>>(Q, Km, Vm, Pm, Cb, AttO);
    gemm_bias<<<dim3(NFEAT / 64, M / 64),     blk, 0, stream>>>(AttO, Wout, bout,    out,  M,     NFEAT, NFEAT);
}

// Round 2
// 570.597 us; speedup vs baseline: 4.9831x; 4.9831x over previous
//
#include <hip/hip_runtime.h>

typedef float f4 __attribute__((ext_vector_type(4)));
typedef __attribute__((ext_vector_type(8))) short bf16x8;
typedef __attribute__((ext_vector_type(4))) short s16x4;
typedef __attribute__((ext_vector_type(4))) float f32x4;

#define T_SEQ 2048
#define NFEAT 512
#define NHEAD 8
#define DK    64
#define BATCH 4

static __device__ __forceinline__ short f2bf(float f) {
    unsigned u = __builtin_bit_cast(unsigned, f);
    u += 0x7fff + ((u >> 16) & 1);          // round-to-nearest-even
    return (short)(u >> 16);
}

// C[M,N] = A[M,K] @ W[N,K]^T + bias ; 64x64 tile, 16x16 threads, 4x4 per thread (fp32)
__global__ __launch_bounds__(256) void gemm_bias(
    const float* __restrict__ A,
    const float* __restrict__ W,
    const float* __restrict__ bias,
    float* __restrict__ C,
    int M, int N, int K)
{
    __shared__ float As[16][64];   // [k][m]
    __shared__ float Ws[16][64];   // [k][n]
    const int tid = threadIdx.x;
    const int tx = tid & 15, ty = tid >> 4;
    const int row0 = blockIdx.y * 64, col0 = blockIdx.x * 64;
    const int lr = tid >> 2;            // 0..63
    const int lc = (tid & 3) * 4;       // 0,4,8,12

    float acc[4][4] = {};
    for (int k0 = 0; k0 < K; k0 += 16) {
        f4 a = *(const f4*)(A + (size_t)(row0 + lr) * K + k0 + lc);
        f4 w = *(const f4*)(W + (size_t)(col0 + lr) * K + k0 + lc);
#pragma unroll
        for (int i = 0; i < 4; ++i) As[lc + i][lr] = a[i];
#pragma unroll
        for (int i = 0; i < 4; ++i) Ws[lc + i][lr] = w[i];
        __syncthreads();
#pragma unroll
        for (int kk = 0; kk < 16; ++kk) {
            f4 av = *(const f4*)&As[kk][ty * 4];
            f4 wv = *(const f4*)&Ws[kk][tx * 4];
#pragma unroll
            for (int i = 0; i < 4; ++i)
#pragma unroll
                for (int j = 0; j < 4; ++j)
                    acc[i][j] += av[i] * wv[j];
        }
        __syncthreads();
    }
    float bv[4] = {0.f, 0.f, 0.f, 0.f};
    if (bias) {
#pragma unroll
        for (int j = 0; j < 4; ++j) bv[j] = bias[col0 + tx * 4 + j];
    }
#pragma unroll
    for (int i = 0; i < 4; ++i) {
        f4 o;
#pragma unroll
        for (int j = 0; j < 4; ++j) o[j] = acc[i][j] + bv[j];
        *(f4*)(C + (size_t)(row0 + ty * 4 + i) * N + col0 + tx * 4) = o;
    }
}

// c[b,h,s] = u[h]·k[b,h,s,:] + vb[h]·p[h,s,:]
__global__ __launch_bounds__(256) void cbias_kernel(
    const float* __restrict__ k, const float* __restrict__ p,
    const float* __restrict__ u, const float* __restrict__ vb,
    float* __restrict__ c)
{
    int idx = blockIdx.x * 256 + threadIdx.x;   // (b*H+h)*T + s
    int s  = idx & (T_SEQ - 1);
    int bh = idx >> 11;
    int b = bh >> 3, h = bh & 7;
    const float* kr = k + (size_t)(b * T_SEQ + s) * NFEAT + h * DK;
    const float* pr = p + (size_t)s * NFEAT + h * DK;
    const float* ur = u + h * DK;
    const float* vr = vb + h * DK;
    float acc = 0.f;
#pragma unroll 4
    for (int d = 0; d < DK; ++d) acc += ur[d] * kr[d] + vr[d] * pr[d];
    c[idx] = acc;
}

// Flash attention over KP = K + P with additive key bias c, scale 1/8.
// bf16 MFMA (16x16x32). grid: (T/64, B*H); block 256 (4 waves, 16 Q-rows each).
// LDS rows padded to 72 bf16 (144 B = 36 words, !=0 mod 32 -> uniform banks; 16B-aligned).
__global__ __launch_bounds__(256) void attn_kernel(
    const float* __restrict__ q, const float* __restrict__ k,
    const float* __restrict__ v, const float* __restrict__ p,
    const float* __restrict__ cbias, float* __restrict__ o)
{
    __shared__ __align__(16) short Qs[64][72];      // [t][d]
    __shared__ __align__(16) short KPs[64][72];     // [s][d]
    __shared__ __align__(16) short Vts[64][72];     // [d][s]
    __shared__ __align__(16) short Ps[4][16][72];   // per-wave P [t][s]
    __shared__ float cs[64];

    const int tid = threadIdx.x;
    const int lane = tid & 63;
    const int wave = tid >> 6;
    const int col = lane & 15;
    const int quad = lane >> 4;
    const int bh = blockIdx.y, b = bh >> 3, h = bh & 7;
    const int t0 = blockIdx.x * 64;
    const int lr = tid >> 2;          // 0..63
    const int lc = (tid & 3) * 16;    // 0,16,32,48

    // stage Q tile (bf16)
    {
        const float* qp = q + (size_t)(b * T_SEQ + t0 + lr) * NFEAT + h * DK + lc;
#pragma unroll
        for (int i = 0; i < 16; i += 4) {
            f4 qv = *(const f4*)(qp + i);
            s16x4 sq;
#pragma unroll
            for (int j = 0; j < 4; ++j) sq[j] = f2bf(qv[j]);
            *(s16x4*)&Qs[lr][lc + i] = sq;
        }
    }

    f32x4 Oacc[4];
    float m_[4], l_[4];
#pragma unroll
    for (int i = 0; i < 4; ++i) {
        m_[i] = -1e30f; l_[i] = 0.f;
        Oacc[i] = (f32x4){0.f, 0.f, 0.f, 0.f};
    }

    for (int s0 = 0; s0 < T_SEQ; s0 += 64) {
        __syncthreads();   // prior-iter LDS reads done (also fences Q staging)
        const float* kr = k + (size_t)(b * T_SEQ + s0 + lr) * NFEAT + h * DK + lc;
        const float* pr = p + (size_t)(s0 + lr) * NFEAT + h * DK + lc;
        const float* vr = v + (size_t)(b * T_SEQ + s0 + lr) * NFEAT + h * DK + lc;
#pragma unroll
        for (int i = 0; i < 16; i += 4) {
            f4 kv = *(const f4*)(kr + i);
            f4 pv = *(const f4*)(pr + i);
            f4 kp = kv + pv;
            s16x4 sk;
#pragma unroll
            for (int j = 0; j < 4; ++j) sk[j] = f2bf(kp[j]);
            *(s16x4*)&KPs[lr][lc + i] = sk;
            f4 vv = *(const f4*)(vr + i);
#pragma unroll
            for (int j = 0; j < 4; ++j) Vts[lc + i + j][lr] = f2bf(vv[j]);
        }
        if (tid < 64) cs[tid] = cbias[(size_t)bh * T_SEQ + s0 + tid];
        __syncthreads();

        // S(16x64 per wave) = Q @ KP^T
        f32x4 Sacc[4];
#pragma unroll
        for (int nt = 0; nt < 4; ++nt) Sacc[nt] = (f32x4){0.f, 0.f, 0.f, 0.f};
#pragma unroll
        for (int kt = 0; kt < 2; ++kt) {
            bf16x8 a = *(const bf16x8*)&Qs[wave * 16 + col][kt * 32 + quad * 8];
#pragma unroll
            for (int nt = 0; nt < 4; ++nt) {
                bf16x8 bb = *(const bf16x8*)&KPs[nt * 16 + col][kt * 32 + quad * 8];
                Sacc[nt] = __builtin_amdgcn_mfma_f32_16x16x32_bf16(a, bb, Sacc[nt], 0, 0, 0);
            }
        }

        // online softmax; lane holds rows quad*4+reg, cols {nt*16+col}
        float alpha[4];
        float c0 = cs[col], c1 = cs[16 + col], c2 = cs[32 + col], c3 = cs[48 + col];
#pragma unroll
        for (int reg = 0; reg < 4; ++reg) {
            float s0v = (Sacc[0][reg] + c0) * 0.125f;
            float s1v = (Sacc[1][reg] + c1) * 0.125f;
            float s2v = (Sacc[2][reg] + c2) * 0.125f;
            float s3v = (Sacc[3][reg] + c3) * 0.125f;
            float rm = fmaxf(fmaxf(s0v, s1v), fmaxf(s2v, s3v));
#pragma unroll
            for (int off = 1; off < 16; off <<= 1) rm = fmaxf(rm, __shfl_xor(rm, off));
            float mn = fmaxf(m_[reg], rm);
            float al = __expf(m_[reg] - mn);
            float e0 = __expf(s0v - mn), e1 = __expf(s1v - mn);
            float e2 = __expf(s2v - mn), e3 = __expf(s3v - mn);
            float rs = e0 + e1 + e2 + e3;
#pragma unroll
            for (int off = 1; off < 16; off <<= 1) rs += __shfl_xor(rs, off);
            l_[reg] = l_[reg] * al + rs;
            m_[reg] = mn;
            alpha[reg] = al;
            int r = quad * 4 + reg;
            Ps[wave][r][col]      = f2bf(e0);
            Ps[wave][r][16 + col] = f2bf(e1);
            Ps[wave][r][32 + col] = f2bf(e2);
            Ps[wave][r][48 + col] = f2bf(e3);
        }
#pragma unroll
        for (int dt = 0; dt < 4; ++dt)
#pragma unroll
            for (int reg = 0; reg < 4; ++reg) Oacc[dt][reg] *= alpha[reg];

        __syncthreads();   // P writes visible / ordered before A-frag reads

        // O += P @ V   (A = Ps[t][s], B = V[s][d] via Vts[d][s])
#pragma unroll
        for (int kt = 0; kt < 2; ++kt) {
            bf16x8 pa = *(const bf16x8*)&Ps[wave][col][kt * 32 + quad * 8];
#pragma unroll
            for (int dt = 0; dt < 4; ++dt) {
                bf16x8 vb = *(const bf16x8*)&Vts[dt * 16 + col][kt * 32 + quad * 8];
                Oacc[dt] = __builtin_amdgcn_mfma_f32_16x16x32_bf16(pa, vb, Oacc[dt], 0, 0, 0);
            }
        }
    }

    // epilogue: O[t][h*64+d] = Oacc/l
#pragma unroll
    for (int reg = 0; reg < 4; ++reg) {
        float inv = 1.f / l_[reg];
        int t = t0 + wave * 16 + quad * 4 + reg;
        float* op = o + (size_t)(b * T_SEQ + t) * NFEAT + h * DK;
#pragma unroll
        for (int dt = 0; dt < 4; ++dt)
            op[dt * 16 + col] = Oacc[dt][reg] * inv;
    }
}

extern "C" void kernel_launch(void* const* d_in, const int* in_sizes, int n_in,
                              void* d_out, int out_size, void* d_ws, size_t ws_size,
                              hipStream_t stream)
{
    const float* x    = (const float*)d_in[0];
    const float* pos  = (const float*)d_in[1];
    const float* Wq   = (const float*)d_in[2];
    const float* bq   = (const float*)d_in[3];
    const float* Wk   = (const float*)d_in[4];
    const float* bk   = (const float*)d_in[5];
    const float* Wv   = (const float*)d_in[6];
    const float* bv   = (const float*)d_in[7];
    const float* Wpos = (const float*)d_in[8];
    const float* Wout = (const float*)d_in[9];
    const float* bout = (const float*)d_in[10];
    const float* pbu  = (const float*)d_in[11];
    const float* pbv  = (const float*)d_in[12];
    float* out = (float*)d_out;

    const int M = BATCH * T_SEQ;  // 8192
    float* ws   = (float*)d_ws;
    float* Q    = ws;
    float* Km   = Q   + (size_t)M * NFEAT;
    float* Vm   = Km  + (size_t)M * NFEAT;
    float* Pm   = Vm  + (size_t)M * NFEAT;
    float* Cb   = Pm  + (size_t)T_SEQ * NFEAT;
    float* AttO = Cb  + (size_t)BATCH * NHEAD * T_SEQ;

    dim3 blk(256);
    gemm_bias<<<dim3(NFEAT / 64, M / 64),     blk, 0, stream>>>(x,    Wq,   bq,      Q,    M,     NFEAT, NFEAT);
    gemm_bias<<<dim3(NFEAT / 64, M / 64),     blk, 0, stream>>>(x,    Wk,   bk,      Km,   M,     NFEAT, NFEAT);
    gemm_bias<<<dim3(NFEAT / 64, M / 64),     blk, 0, stream>>>(x,    Wv,   bv,      Vm,   M,     NFEAT, NFEAT);
    gemm_bias<<<dim3(NFEAT / 64, T_SEQ / 64), blk, 0, stream>>>(pos,  Wpos, nullptr, Pm,   T_SEQ, NFEAT, NFEAT);
    cbias_kernel<<<dim3(BATCH * NHEAD * T_SEQ / 256), blk, 0, stream>>>(Km, Pm, pbu, pbv, Cb);
    attn_kernel<<<dim3(T_SEQ / 64, BATCH * NHEAD), blk, 0, stream>>>(Q, Km, Vm, Pm, Cb, AttO);
    gemm_bias<<<dim3(NFEAT / 64, M / 64),     blk, 0, stream>>>(AttO, Wout, bout,    out,  M,     NFEAT, NFEAT);
}

// Round 3
// 254.839 us; speedup vs baseline: 11.1573x; 2.2390x over previous
//
#include <hip/hip_runtime.h>

typedef float f4 __attribute__((ext_vector_type(4)));
typedef __attribute__((ext_vector_type(8))) short bf16x8;
typedef __attribute__((ext_vector_type(4))) float f32x4;

#define T_SEQ 2048
#define NFEAT 512
#define NHEAD 8
#define DK    64
#define BATCH 4

using gptr_t = const __attribute__((address_space(1))) void*;
using lptr_t = __attribute__((address_space(3))) void*;

static __device__ __forceinline__ short f2bf(float f) {
    unsigned u = __builtin_bit_cast(unsigned, f);
    u += 0x7fff + ((u >> 16) & 1);          // round-to-nearest-even
    return (short)(u >> 16);
}
static __device__ __forceinline__ float b2f(short s) {
    unsigned u = ((unsigned)(unsigned short)s) << 16;
    return __builtin_bit_cast(float, u);
}

// ---------------- fused fp32->bf16 conversion + weight/bias packing -------------
// regions (blocks of 2048 elems): x:2048, pos:512, Wq/Wk/Wv:128 each, Wpos:128, Wout:128, +1 bias block
__global__ __launch_bounds__(256) void cvt_kernel(
    const float* __restrict__ x, const float* __restrict__ pos,
    const float* __restrict__ Wq, const float* __restrict__ Wk, const float* __restrict__ Wv,
    const float* __restrict__ Wpos, const float* __restrict__ Wout,
    const float* __restrict__ bq, const float* __restrict__ bk, const float* __restrict__ bv,
    short* __restrict__ xb, short* __restrict__ posb, short* __restrict__ wqkv,
    short* __restrict__ wpb, short* __restrict__ wob, float* __restrict__ bqkv)
{
    const int blk = blockIdx.x;
    const float* src; short* dst; int off;
    if      (blk < 2048) { src = x;    dst = wqkv; dst = xb;          off = blk * 2048; }
    else if (blk < 2560) { src = pos;  dst = posb;                    off = (blk - 2048) * 2048; }
    else if (blk < 2688) { src = Wq;   dst = wqkv;                    off = (blk - 2560) * 2048; }
    else if (blk < 2816) { src = Wk;   dst = wqkv + 262144;           off = (blk - 2688) * 2048; }
    else if (blk < 2944) { src = Wv;   dst = wqkv + 524288;           off = (blk - 2816) * 2048; }
    else if (blk < 3072) { src = Wpos; dst = wpb;                     off = (blk - 2944) * 2048; }
    else if (blk < 3200) { src = Wout; dst = wob;                     off = (blk - 3072) * 2048; }
    else {
        int t = threadIdx.x;           // 256 threads cover 512 each x2
        bqkv[t]        = bq[t];        bqkv[256 + t]  = bq[256 + t];
        bqkv[512 + t]  = bk[t];        bqkv[768 + t]  = bk[256 + t];
        bqkv[1024 + t] = bv[t];        bqkv[1280 + t] = bv[256 + t];
        return;
    }
    int i = off + threadIdx.x * 8;
    f4 a = *(const f4*)(src + i);
    f4 b = *(const f4*)(src + i + 4);
    bf16x8 o;
#pragma unroll
    for (int j = 0; j < 4; ++j) { o[j] = f2bf(a[j]); o[4 + j] = f2bf(b[j]); }
    *(bf16x8*)(dst + i) = o;
}

// ---------------- bf16 MFMA GEMM: C[M,N] = A[M,K] @ B[N,K]^T + bias ------------
// 128x128 tile, BK=32, 4 waves (2x2), global_load_lds w/ k-chunk-major LDS groups.
template<int OUT_BF16>
__global__ __launch_bounds__(256) void gemm_bf16(
    const short* __restrict__ A, const short* __restrict__ B,
    const float* __restrict__ bias, void* __restrict__ Cv,
    int M, int N, int K)
{
    __shared__ short As[4096];   // 8 groups x 512 shorts; group g = rows 16g..16g+15
    __shared__ short Bs[4096];   // within group: chunk-major: off = g*512 + kc*128 + rl*8
    const int tid = threadIdx.x, lane = tid & 63, wave = tid >> 6;
    const int col = lane & 15, quad = lane >> 4;
    const int wm = (wave >> 1) * 64, wn = (wave & 1) * 64;
    const int row0 = blockIdx.y * 128, col0 = blockIdx.x * 128;
    const int rl = lane & 15, kc = lane >> 4;

    const size_t Aoff = (size_t)(row0 + wave * 32 + rl) * K + kc * 8;
    const size_t Boff = (size_t)(col0 + wave * 32 + rl) * K + kc * 8;

    f32x4 acc[4][4];
#pragma unroll
    for (int i = 0; i < 4; ++i)
#pragma unroll
        for (int j = 0; j < 4; ++j) acc[i][j] = (f32x4){0.f, 0.f, 0.f, 0.f};

    for (int k0 = 0; k0 < K; k0 += 32) {
        __syncthreads();
        __builtin_amdgcn_global_load_lds((gptr_t)(A + Aoff + k0),          (lptr_t)(As + wave * 1024),       16, 0, 0);
        __builtin_amdgcn_global_load_lds((gptr_t)(A + Aoff + 16 * K + k0), (lptr_t)(As + wave * 1024 + 512), 16, 0, 0);
        __builtin_amdgcn_global_load_lds((gptr_t)(B + Boff + k0),          (lptr_t)(Bs + wave * 1024),       16, 0, 0);
        __builtin_amdgcn_global_load_lds((gptr_t)(B + Boff + 16 * K + k0), (lptr_t)(Bs + wave * 1024 + 512), 16, 0, 0);
        __syncthreads();
        bf16x8 af[4], bfr[4];
#pragma unroll
        for (int mt = 0; mt < 4; ++mt)
            af[mt] = *(const bf16x8*)&As[((wm >> 4) + mt) * 512 + quad * 128 + col * 8];
#pragma unroll
        for (int nt = 0; nt < 4; ++nt)
            bfr[nt] = *(const bf16x8*)&Bs[((wn >> 4) + nt) * 512 + quad * 128 + col * 8];
#pragma unroll
        for (int mt = 0; mt < 4; ++mt)
#pragma unroll
            for (int nt = 0; nt < 4; ++nt)
                acc[mt][nt] = __builtin_amdgcn_mfma_f32_16x16x32_bf16(af[mt], bfr[nt], acc[mt][nt], 0, 0, 0);
    }

    float bv4[4];
#pragma unroll
    for (int nt = 0; nt < 4; ++nt)
        bv4[nt] = bias ? bias[col0 + wn + nt * 16 + col] : 0.f;
#pragma unroll
    for (int mt = 0; mt < 4; ++mt)
#pragma unroll
        for (int reg = 0; reg < 4; ++reg) {
            int r = row0 + wm + mt * 16 + quad * 4 + reg;
#pragma unroll
            for (int nt = 0; nt < 4; ++nt) {
                int c = col0 + wn + nt * 16 + col;
                float v = acc[mt][nt][reg] + bv4[nt];
                if (OUT_BF16) ((short*)Cv)[(size_t)r * N + c] = f2bf(v);
                else          ((float*)Cv)[(size_t)r * N + c] = v;
            }
        }
}

// ---------------- KP = K + P (bf16), cbias = 0.125*(u.k + vb.p) ----------------
__global__ __launch_bounds__(256) void kpcb_kernel(
    const short* __restrict__ qkv, const short* __restrict__ pm,
    const float* __restrict__ u, const float* __restrict__ vb,
    short* __restrict__ kp, float* __restrict__ cb)
{
    int w = blockIdx.x * 4 + (threadIdx.x >> 6);
    int lane = threadIdx.x & 63;
    int s = w & (T_SEQ - 1), bh = w >> 11, b = bh >> 3, h = bh & 7;
    float k = b2f(qkv[(size_t)(b * T_SEQ + s) * 1536 + 512 + h * DK + lane]);
    float p = b2f(pm[(size_t)s * NFEAT + h * DK + lane]);
    kp[((size_t)bh * T_SEQ + s) * DK + lane] = f2bf(k + p);
    float c = u[h * DK + lane] * k + vb[h * DK + lane] * p;
#pragma unroll
    for (int off = 1; off < 64; off <<= 1) c += __shfl_xor(c, off);
    if (lane == 0) cb[(size_t)bh * T_SEQ + s] = 0.125f * c;
}

// ---------------- V transpose: Vt[bh][d][t] from QKV V-columns -----------------
__global__ __launch_bounds__(256) void vtr_kernel(
    const short* __restrict__ qkv, short* __restrict__ vt)
{
    __shared__ short tile[64][72];
    int tid = threadIdx.x, lr = tid >> 2, lc = (tid & 3) * 16;
    int bh = blockIdx.y, b = bh >> 3, h = bh & 7, t0 = blockIdx.x * 64;
    const short* src = qkv + (size_t)(b * T_SEQ + t0 + lr) * 1536 + 1024 + h * DK + lc;
    *(bf16x8*)&tile[lr][lc]     = *(const bf16x8*)src;
    *(bf16x8*)&tile[lr][lc + 8] = *(const bf16x8*)(src + 8);
    __syncthreads();
    short* dst = vt + (size_t)(bh * DK + lr) * T_SEQ + t0 + lc;
    bf16x8 o0, o1;
#pragma unroll
    for (int j = 0; j < 8; ++j) { o0[j] = tile[lc + j][lr]; o1[j] = tile[lc + 8 + j][lr]; }
    *(bf16x8*)dst       = o0;
    *(bf16x8*)(dst + 8) = o1;
}

// ---------------- flash attention, bf16 MFMA, no-max softmax -------------------
__global__ __launch_bounds__(256) void attn_kernel(
    const short* __restrict__ qkv, const short* __restrict__ kp,
    const short* __restrict__ vt, const float* __restrict__ cb,
    short* __restrict__ attO)
{
    __shared__ __align__(16) short Qs[64][72], KPs[64][72], Vts[64][72], Ps[4][16][72];
    __shared__ float cs[64];
    const int tid = threadIdx.x, lane = tid & 63, wave = tid >> 6;
    const int col = lane & 15, quad = lane >> 4;
    const int bh = blockIdx.y, b = bh >> 3, h = bh & 7, t0 = blockIdx.x * 64;
    const int lr = tid >> 2, lc = (tid & 3) * 16;

    {
        const short* qp = qkv + (size_t)(b * T_SEQ + t0 + lr) * 1536 + h * DK + lc;
        *(bf16x8*)&Qs[lr][lc]     = *(const bf16x8*)qp;
        *(bf16x8*)&Qs[lr][lc + 8] = *(const bf16x8*)(qp + 8);
    }
    f32x4 Oacc[4];
    float lsum[4] = {0.f, 0.f, 0.f, 0.f};
#pragma unroll
    for (int i = 0; i < 4; ++i) Oacc[i] = (f32x4){0.f, 0.f, 0.f, 0.f};

    for (int s0 = 0; s0 < T_SEQ; s0 += 64) {
        __syncthreads();
        {
            const short* kpp = kp + ((size_t)bh * T_SEQ + s0 + lr) * DK + lc;
            *(bf16x8*)&KPs[lr][lc]     = *(const bf16x8*)kpp;
            *(bf16x8*)&KPs[lr][lc + 8] = *(const bf16x8*)(kpp + 8);
            const short* vp = vt + (size_t)(bh * DK + lr) * T_SEQ + s0 + lc;
            *(bf16x8*)&Vts[lr][lc]     = *(const bf16x8*)vp;
            *(bf16x8*)&Vts[lr][lc + 8] = *(const bf16x8*)(vp + 8);
            if (tid < 64) cs[tid] = cb[(size_t)bh * T_SEQ + s0 + tid];
        }
        __syncthreads();

        f32x4 S[4];
#pragma unroll
        for (int nt = 0; nt < 4; ++nt) S[nt] = (f32x4){0.f, 0.f, 0.f, 0.f};
#pragma unroll
        for (int kt = 0; kt < 2; ++kt) {
            bf16x8 a = *(const bf16x8*)&Qs[wave * 16 + col][kt * 32 + quad * 8];
#pragma unroll
            for (int nt = 0; nt < 4; ++nt) {
                bf16x8 bb = *(const bf16x8*)&KPs[nt * 16 + col][kt * 32 + quad * 8];
                S[nt] = __builtin_amdgcn_mfma_f32_16x16x32_bf16(a, bb, S[nt], 0, 0, 0);
            }
        }
        // exp without max subtraction (|score| << 88, fp32-safe); lane-local l
        float c0 = cs[col], c1 = cs[16 + col], c2 = cs[32 + col], c3 = cs[48 + col];
#pragma unroll
        for (int reg = 0; reg < 4; ++reg) {
            int r = quad * 4 + reg;
            float e0 = __expf(fmaf(S[0][reg], 0.125f, c0));
            float e1 = __expf(fmaf(S[1][reg], 0.125f, c1));
            float e2 = __expf(fmaf(S[2][reg], 0.125f, c2));
            float e3 = __expf(fmaf(S[3][reg], 0.125f, c3));
            lsum[reg] += (e0 + e1) + (e2 + e3);
            Ps[wave][r][col]      = f2bf(e0);
            Ps[wave][r][16 + col] = f2bf(e1);
            Ps[wave][r][32 + col] = f2bf(e2);
            Ps[wave][r][48 + col] = f2bf(e3);
        }
        __syncthreads();
#pragma unroll
        for (int kt = 0; kt < 2; ++kt) {
            bf16x8 pa = *(const bf16x8*)&Ps[wave][col][kt * 32 + quad * 8];
#pragma unroll
            for (int dt = 0; dt < 4; ++dt) {
                bf16x8 vb = *(const bf16x8*)&Vts[dt * 16 + col][kt * 32 + quad * 8];
                Oacc[dt] = __builtin_amdgcn_mfma_f32_16x16x32_bf16(pa, vb, Oacc[dt], 0, 0, 0);
            }
        }
    }
#pragma unroll
    for (int reg = 0; reg < 4; ++reg) {
        float l = lsum[reg];
#pragma unroll
        for (int off = 1; off < 16; off <<= 1) l += __shfl_xor(l, off);
        float inv = 1.f / l;
        int t = t0 + wave * 16 + quad * 4 + reg;
        short* op = attO + (size_t)(b * T_SEQ + t) * NFEAT + h * DK;
#pragma unroll
        for (int dt = 0; dt < 4; ++dt)
            op[dt * 16 + col] = f2bf(Oacc[dt][reg] * inv);
    }
}

extern "C" void kernel_launch(void* const* d_in, const int* in_sizes, int n_in,
                              void* d_out, int out_size, void* d_ws, size_t ws_size,
                              hipStream_t stream)
{
    const float* x    = (const float*)d_in[0];
    const float* pos  = (const float*)d_in[1];
    const float* Wq   = (const float*)d_in[2];
    const float* bq   = (const float*)d_in[3];
    const float* Wk   = (const float*)d_in[4];
    const float* bk   = (const float*)d_in[5];
    const float* Wv   = (const float*)d_in[6];
    const float* bv   = (const float*)d_in[7];
    const float* Wpos = (const float*)d_in[8];
    const float* Wout = (const float*)d_in[9];
    const float* bout = (const float*)d_in[10];
    const float* pbu  = (const float*)d_in[11];
    const float* pbv  = (const float*)d_in[12];
    float* out = (float*)d_out;

    short* xb   = (short*)d_ws;            // 4,194,304
    short* posb = xb   + 4194304;          // 1,048,576
    short* wqkv = posb + 1048576;          //   786,432
    short* wpb  = wqkv + 786432;           //   262,144
    short* wob  = wpb  + 262144;           //   262,144
    short* QKV  = wob  + 262144;           // 12,582,912  [8192][1536] (Q|K|V)
    short* Pm   = QKV  + 12582912;         // 1,048,576   [2048][512]
    short* KP   = Pm   + 1048576;          // 4,194,304   [bh][s][64]
    short* Vt   = KP   + 4194304;          // 4,194,304   [bh][d][t]
    short* AttO = Vt   + 4194304;          // 4,194,304   [8192][512]
    float* bqkv = (float*)(AttO + 4194304);
    float* Cb   = bqkv + 1536;             // 65,536

    dim3 blk(256);
    cvt_kernel<<<dim3(3201), blk, 0, stream>>>(x, pos, Wq, Wk, Wv, Wpos, Wout, bq, bk, bv,
                                               xb, posb, wqkv, wpb, wob, bqkv);
    gemm_bf16<1><<<dim3(1536 / 128, 8192 / 128), blk, 0, stream>>>(xb,   wqkv, bqkv,    QKV, 8192, 1536, 512);
    gemm_bf16<1><<<dim3(512 / 128,  2048 / 128), blk, 0, stream>>>(posb, wpb,  nullptr, Pm,  2048, 512,  512);
    kpcb_kernel<<<dim3(BATCH * NHEAD * T_SEQ / 4), blk, 0, stream>>>(QKV, Pm, pbu, pbv, KP, Cb);
    vtr_kernel<<<dim3(T_SEQ / 64, BATCH * NHEAD), blk, 0, stream>>>(QKV, Vt);
    attn_kernel<<<dim3(T_SEQ / 64, BATCH * NHEAD), blk, 0, stream>>>(QKV, KP, Vt, Cb, AttO);
    gemm_bf16<0><<<dim3(512 / 128,  8192 / 128), blk, 0, stream>>>(AttO, wob, bout, out, 8192, 512, 512);
}

// Round 4
// 235.984 us; speedup vs baseline: 12.0488x; 1.0799x over previous
//
#include <hip/hip_runtime.h>

typedef float f4 __attribute__((ext_vector_type(4)));
typedef __attribute__((ext_vector_type(8))) short bf16x8;
typedef __attribute__((ext_vector_type(4))) float f32x4;

#define T_SEQ 2048
#define NFEAT 512
#define NHEAD 8
#define DK    64
#define BATCH 4

using gptr_t = const __attribute__((address_space(1))) void*;
using lptr_t = __attribute__((address_space(3))) void*;

static __device__ __forceinline__ short f2bf(float f) {
    unsigned u = __builtin_bit_cast(unsigned, f);
    u += 0x7fff + ((u >> 16) & 1);          // round-to-nearest-even
    return (short)(u >> 16);
}
static __device__ __forceinline__ float b2f(short s) {
    unsigned u = ((unsigned)(unsigned short)s) << 16;
    return __builtin_bit_cast(float, u);
}

// ---------------- fused fp32->bf16 conversion + weight/bias packing -------------
__global__ __launch_bounds__(256) void cvt_kernel(
    const float* __restrict__ x, const float* __restrict__ pos,
    const float* __restrict__ Wq, const float* __restrict__ Wk, const float* __restrict__ Wv,
    const float* __restrict__ Wpos, const float* __restrict__ Wout,
    const float* __restrict__ bq, const float* __restrict__ bk, const float* __restrict__ bv,
    short* __restrict__ xb, short* __restrict__ posb, short* __restrict__ wqkv,
    short* __restrict__ wpb, short* __restrict__ wob, float* __restrict__ bqkv)
{
    const int blk = blockIdx.x;
    const float* src; short* dst; int off;
    if      (blk < 2048) { src = x;    dst = xb;          off = blk * 2048; }
    else if (blk < 2560) { src = pos;  dst = posb;        off = (blk - 2048) * 2048; }
    else if (blk < 2688) { src = Wq;   dst = wqkv;        off = (blk - 2560) * 2048; }
    else if (blk < 2816) { src = Wk;   dst = wqkv + 262144; off = (blk - 2688) * 2048; }
    else if (blk < 2944) { src = Wv;   dst = wqkv + 524288; off = (blk - 2816) * 2048; }
    else if (blk < 3072) { src = Wpos; dst = wpb;         off = (blk - 2944) * 2048; }
    else if (blk < 3200) { src = Wout; dst = wob;         off = (blk - 3072) * 2048; }
    else {
        int t = threadIdx.x;
        bqkv[t]        = bq[t];        bqkv[256 + t]  = bq[256 + t];
        bqkv[512 + t]  = bk[t];        bqkv[768 + t]  = bk[256 + t];
        bqkv[1024 + t] = bv[t];        bqkv[1280 + t] = bv[256 + t];
        return;
    }
    int i = off + threadIdx.x * 8;
    f4 a = *(const f4*)(src + i);
    f4 b = *(const f4*)(src + i + 4);
    bf16x8 o;
#pragma unroll
    for (int j = 0; j < 4; ++j) { o[j] = f2bf(a[j]); o[4 + j] = f2bf(b[j]); }
    *(bf16x8*)(dst + i) = o;
}

// ---------------- bf16 MFMA GEMM tile: C[128,128] = A@B^T + bias ---------------
// BK=64, 4 waves (2x2). LDS: 8 groups of 16 rows, chunk-major:
//   off(g, rl, kc) = g*1024 + kc*128 + rl*8 shorts  (kc = k-chunk of 8)
// Staged via global_load_lds w=16 (lane -> base + lane*16B matches layout).
// Fragment reads land on banks 4*col mod 32 -> 2-way = free.
template<int OUT_BF16>
static __device__ __forceinline__ void gemm_tile(
    short* As, short* Bs,
    const short* __restrict__ A, const short* __restrict__ B,
    const float* __restrict__ bias, void* __restrict__ Cv,
    int N, int K, int row0, int col0)
{
    const int tid = threadIdx.x, lane = tid & 63, wave = tid >> 6;
    const int col = lane & 15, quad = lane >> 4;
    const int wm = (wave >> 1) * 64, wn = (wave & 1) * 64;
    const int rl = lane & 15;

    const short* Abase = A + (size_t)(row0 + wave * 32 + rl) * K + (lane >> 4) * 8;
    const short* Bbase = B + (size_t)(col0 + wave * 32 + rl) * K + (lane >> 4) * 8;

    f32x4 acc[4][4];
#pragma unroll
    for (int i = 0; i < 4; ++i)
#pragma unroll
        for (int j = 0; j < 4; ++j) acc[i][j] = (f32x4){0.f, 0.f, 0.f, 0.f};

    for (int k0 = 0; k0 < K; k0 += 64) {
        __syncthreads();
#pragma unroll
        for (int c = 0; c < 2; ++c)
#pragma unroll
            for (int hf = 0; hf < 2; ++hf) {
                __builtin_amdgcn_global_load_lds((gptr_t)(Abase + (size_t)(16 * c) * K + k0 + hf * 32),
                                                 (lptr_t)(As + wave * 2048 + c * 1024 + hf * 512), 16, 0, 0);
                __builtin_amdgcn_global_load_lds((gptr_t)(Bbase + (size_t)(16 * c) * K + k0 + hf * 32),
                                                 (lptr_t)(Bs + wave * 2048 + c * 1024 + hf * 512), 16, 0, 0);
            }
        __syncthreads();
#pragma unroll
        for (int kt = 0; kt < 2; ++kt) {
            bf16x8 af[4], bfr[4];
#pragma unroll
            for (int mt = 0; mt < 4; ++mt)
                af[mt] = *(const bf16x8*)&As[((wm >> 4) + mt) * 1024 + (kt * 4 + quad) * 128 + col * 8];
#pragma unroll
            for (int nt = 0; nt < 4; ++nt)
                bfr[nt] = *(const bf16x8*)&Bs[((wn >> 4) + nt) * 1024 + (kt * 4 + quad) * 128 + col * 8];
#pragma unroll
            for (int mt = 0; mt < 4; ++mt)
#pragma unroll
                for (int nt = 0; nt < 4; ++nt)
                    acc[mt][nt] = __builtin_amdgcn_mfma_f32_16x16x32_bf16(af[mt], bfr[nt], acc[mt][nt], 0, 0, 0);
        }
    }

    float bv4[4];
#pragma unroll
    for (int nt = 0; nt < 4; ++nt)
        bv4[nt] = bias ? bias[col0 + wn + nt * 16 + col] : 0.f;
#pragma unroll
    for (int mt = 0; mt < 4; ++mt)
#pragma unroll
        for (int reg = 0; reg < 4; ++reg) {
            int r = row0 + wm + mt * 16 + quad * 4 + reg;
#pragma unroll
            for (int nt = 0; nt < 4; ++nt) {
                int c = col0 + wn + nt * 16 + col;
                float v = acc[mt][nt][reg] + bv4[nt];
                if (OUT_BF16) ((short*)Cv)[(size_t)r * N + c] = f2bf(v);
                else          ((float*)Cv)[(size_t)r * N + c] = v;
            }
        }
}

// QKV (768 tiles) + pos (64 tiles) in one dispatch
__global__ __launch_bounds__(256) void gemm_qkv_pos(
    const short* __restrict__ xb, const short* __restrict__ wqkv,
    const float* __restrict__ bqkv, short* __restrict__ QKV,
    const short* __restrict__ posb, const short* __restrict__ wpb,
    short* __restrict__ Pm)
{
    __shared__ short As[8192], Bs[8192];
    const int bid = blockIdx.x;
    if (bid < 768) {
        gemm_tile<1>(As, Bs, xb, wqkv, bqkv, QKV, 1536, 512, (bid / 12) * 128, (bid % 12) * 128);
    } else {
        const int t = bid - 768;
        gemm_tile<1>(As, Bs, posb, wpb, nullptr, Pm, 512, 512, (t / 4) * 128, (t % 4) * 128);
    }
}

__global__ __launch_bounds__(256) void gemm_out_kernel(
    const short* __restrict__ A, const short* __restrict__ B,
    const float* __restrict__ bias, float* __restrict__ C)
{
    __shared__ short As[8192], Bs[8192];
    gemm_tile<0>(As, Bs, A, B, bias, C, 512, 512, blockIdx.y * 128, blockIdx.x * 128);
}

// ---------------- fused: KP = K+P, cbias = 0.125*(u.k+vb.p), Vt transpose ------
__global__ __launch_bounds__(256) void kvprep_kernel(
    const short* __restrict__ qkv, const short* __restrict__ pm,
    const float* __restrict__ u, const float* __restrict__ vb,
    short* __restrict__ kp, short* __restrict__ vt, float* __restrict__ cb)
{
    __shared__ short tile[64][72];
    const int tid = threadIdx.x, lr = tid >> 2, lc = (tid & 3) * 16;
    const int bh = blockIdx.y, b = bh >> 3, h = bh & 7, s0 = blockIdx.x * 64;

    const short* kptr = qkv + (size_t)(b * T_SEQ + s0 + lr) * 1536 + 512 + h * DK + lc;
    const short* pptr = pm + (size_t)(s0 + lr) * NFEAT + h * DK + lc;
    const short* vptr = qkv + (size_t)(b * T_SEQ + s0 + lr) * 1536 + 1024 + h * DK + lc;
    bf16x8 k0_ = *(const bf16x8*)kptr,       k1_ = *(const bf16x8*)(kptr + 8);
    bf16x8 p0_ = *(const bf16x8*)pptr,       p1_ = *(const bf16x8*)(pptr + 8);
    bf16x8 v0_ = *(const bf16x8*)vptr,       v1_ = *(const bf16x8*)(vptr + 8);

    float c = 0.f;
    bf16x8 o0, o1;
#pragma unroll
    for (int j = 0; j < 8; ++j) {
        float kf = b2f(k0_[j]), pf = b2f(p0_[j]);
        o0[j] = f2bf(kf + pf);
        c += u[h * DK + lc + j] * kf + vb[h * DK + lc + j] * pf;
        float kf1 = b2f(k1_[j]), pf1 = b2f(p1_[j]);
        o1[j] = f2bf(kf1 + pf1);
        c += u[h * DK + lc + 8 + j] * kf1 + vb[h * DK + lc + 8 + j] * pf1;
    }
    short* kpd = kp + ((size_t)bh * T_SEQ + s0 + lr) * DK + lc;
    *(bf16x8*)kpd       = o0;
    *(bf16x8*)(kpd + 8) = o1;
    c += __shfl_xor(c, 1);
    c += __shfl_xor(c, 2);
    if ((tid & 3) == 0) cb[(size_t)bh * T_SEQ + s0 + lr] = 0.125f * c;

    *(bf16x8*)&tile[lr][lc]     = v0_;
    *(bf16x8*)&tile[lr][lc + 8] = v1_;
    __syncthreads();
    short* dst = vt + (size_t)(bh * DK + lr) * T_SEQ + s0 + lc;
    bf16x8 t0_, t1_;
#pragma unroll
    for (int j = 0; j < 8; ++j) { t0_[j] = tile[lc + j][lr]; t1_[j] = tile[lc + 8 + j][lr]; }
    *(bf16x8*)dst       = t0_;
    *(bf16x8*)(dst + 8) = t1_;
}

// ---------------- flash attention: 128 Q-rows/block, 8 waves, bf16 MFMA --------
__global__ __launch_bounds__(512) void attn_kernel(
    const short* __restrict__ qkv, const short* __restrict__ kp,
    const short* __restrict__ vt, const float* __restrict__ cb,
    short* __restrict__ attO)
{
    __shared__ __align__(16) short Qs[128][72], KPs[64][72], Vts[64][72], Ps[8][16][72];
    __shared__ float cs[64];
    const int tid = threadIdx.x, lane = tid & 63, wave = tid >> 6;
    const int col = lane & 15, quad = lane >> 4;
    const int bh = blockIdx.y, b = bh >> 3, h = bh & 7, t0 = blockIdx.x * 128;

    {   // Q: 128 rows, 512 threads x 16 shorts
        const int lr = tid >> 2, lc = (tid & 3) * 16;
        const short* qp = qkv + (size_t)(b * T_SEQ + t0 + lr) * 1536 + h * DK + lc;
        *(bf16x8*)&Qs[lr][lc]     = *(const bf16x8*)qp;
        *(bf16x8*)&Qs[lr][lc + 8] = *(const bf16x8*)(qp + 8);
    }
    const int lr8 = tid >> 3, lc8 = (tid & 7) * 8;   // 64x64 staging, 8 shorts/thread

    f32x4 Oacc[4];
    float lsum[4] = {0.f, 0.f, 0.f, 0.f};
#pragma unroll
    for (int i = 0; i < 4; ++i) Oacc[i] = (f32x4){0.f, 0.f, 0.f, 0.f};

    for (int s0 = 0; s0 < T_SEQ; s0 += 64) {
        __syncthreads();
        *(bf16x8*)&KPs[lr8][lc8] = *(const bf16x8*)(kp + ((size_t)bh * T_SEQ + s0 + lr8) * DK + lc8);
        *(bf16x8*)&Vts[lr8][lc8] = *(const bf16x8*)(vt + (size_t)(bh * DK + lr8) * T_SEQ + s0 + lc8);
        if (tid < 64) cs[tid] = cb[(size_t)bh * T_SEQ + s0 + tid];
        __syncthreads();

        f32x4 S[4];
#pragma unroll
        for (int nt = 0; nt < 4; ++nt) S[nt] = (f32x4){0.f, 0.f, 0.f, 0.f};
#pragma unroll
        for (int kt = 0; kt < 2; ++kt) {
            bf16x8 a = *(const bf16x8*)&Qs[wave * 16 + col][kt * 32 + quad * 8];
#pragma unroll
            for (int nt = 0; nt < 4; ++nt) {
                bf16x8 bb = *(const bf16x8*)&KPs[nt * 16 + col][kt * 32 + quad * 8];
                S[nt] = __builtin_amdgcn_mfma_f32_16x16x32_bf16(a, bb, S[nt], 0, 0, 0);
            }
        }
        float c0 = cs[col], c1 = cs[16 + col], c2 = cs[32 + col], c3 = cs[48 + col];
#pragma unroll
        for (int reg = 0; reg < 4; ++reg) {
            int r = quad * 4 + reg;
            float e0 = __expf(fmaf(S[0][reg], 0.125f, c0));
            float e1 = __expf(fmaf(S[1][reg], 0.125f, c1));
            float e2 = __expf(fmaf(S[2][reg], 0.125f, c2));
            float e3 = __expf(fmaf(S[3][reg], 0.125f, c3));
            lsum[reg] += (e0 + e1) + (e2 + e3);
            Ps[wave][r][col]      = f2bf(e0);
            Ps[wave][r][16 + col] = f2bf(e1);
            Ps[wave][r][32 + col] = f2bf(e2);
            Ps[wave][r][48 + col] = f2bf(e3);
        }
        __syncthreads();
#pragma unroll
        for (int kt = 0; kt < 2; ++kt) {
            bf16x8 pa = *(const bf16x8*)&Ps[wave][col][kt * 32 + quad * 8];
#pragma unroll
            for (int dt = 0; dt < 4; ++dt) {
                bf16x8 vb = *(const bf16x8*)&Vts[dt * 16 + col][kt * 32 + quad * 8];
                Oacc[dt] = __builtin_amdgcn_mfma_f32_16x16x32_bf16(pa, vb, Oacc[dt], 0, 0, 0);
            }
        }
    }
#pragma unroll
    for (int reg = 0; reg < 4; ++reg) {
        float l = lsum[reg];
#pragma unroll
        for (int off = 1; off < 16; off <<= 1) l += __shfl_xor(l, off);
        float inv = 1.f / l;
        int t = t0 + wave * 16 + quad * 4 + reg;
        short* op = attO + (size_t)(b * T_SEQ + t) * NFEAT + h * DK;
#pragma unroll
        for (int dt = 0; dt < 4; ++dt)
            op[dt * 16 + col] = f2bf(Oacc[dt][reg] * inv);
    }
}

extern "C" void kernel_launch(void* const* d_in, const int* in_sizes, int n_in,
                              void* d_out, int out_size, void* d_ws, size_t ws_size,
                              hipStream_t stream)
{
    const float* x    = (const float*)d_in[0];
    const float* pos  = (const float*)d_in[1];
    const float* Wq   = (const float*)d_in[2];
    const float* bq   = (const float*)d_in[3];
    const float* Wk   = (const float*)d_in[4];
    const float* bk   = (const float*)d_in[5];
    const float* Wv   = (const float*)d_in[6];
    const float* bv   = (const float*)d_in[7];
    const float* Wpos = (const float*)d_in[8];
    const float* Wout = (const float*)d_in[9];
    const float* bout = (const float*)d_in[10];
    const float* pbu  = (const float*)d_in[11];
    const float* pbv  = (const float*)d_in[12];
    float* out = (float*)d_out;

    short* xb   = (short*)d_ws;            // 4,194,304
    short* posb = xb   + 4194304;          // 1,048,576
    short* wqkv = posb + 1048576;          //   786,432
    short* wpb  = wqkv + 786432;           //   262,144
    short* wob  = wpb  + 262144;           //   262,144
    short* QKV  = wob  + 262144;           // 12,582,912  [8192][1536] (Q|K|V)
    short* Pm   = QKV  + 12582912;         // 1,048,576   [2048][512]
    short* KP   = Pm   + 1048576;          // 4,194,304   [bh][s][64]
    short* Vt   = KP   + 4194304;          // 4,194,304   [bh][d][t]
    short* AttO = Vt   + 4194304;          // 4,194,304   [8192][512]
    float* bqkv = (float*)(AttO + 4194304);
    float* Cb   = bqkv + 1536;             // 65,536

    cvt_kernel<<<dim3(3201), dim3(256), 0, stream>>>(x, pos, Wq, Wk, Wv, Wpos, Wout, bq, bk, bv,
                                                     xb, posb, wqkv, wpb, wob, bqkv);
    gemm_qkv_pos<<<dim3(832), dim3(256), 0, stream>>>(xb, wqkv, bqkv, QKV, posb, wpb, Pm);
    kvprep_kernel<<<dim3(T_SEQ / 64, BATCH * NHEAD), dim3(256), 0, stream>>>(QKV, Pm, pbu, pbv, KP, Vt, Cb);
    attn_kernel<<<dim3(T_SEQ / 128, BATCH * NHEAD), dim3(512), 0, stream>>>(QKV, KP, Vt, Cb, AttO);
    gemm_out_kernel<<<dim3(512 / 128, 8192 / 128), dim3(256), 0, stream>>>(AttO, wob, bout, out);
}

// Round 5
// 215.318 us; speedup vs baseline: 13.2052x; 1.0960x over previous
//
#include <hip/hip_runtime.h>

typedef float f4 __attribute__((ext_vector_type(4)));
typedef __attribute__((ext_vector_type(8))) short bf16x8;
typedef __attribute__((ext_vector_type(4))) float f32x4;

#define T_SEQ 2048
#define NFEAT 512
#define NHEAD 8
#define DK    64
#define BATCH 4

using gptr_t = const __attribute__((address_space(1))) void*;
using lptr_t = __attribute__((address_space(3))) void*;

#define LOG2E_8 0.18033688011f   // 0.125 * log2(e)

static __device__ __forceinline__ short f2bf(float f) {
    unsigned u = __builtin_bit_cast(unsigned, f);
    u += 0x7fff + ((u >> 16) & 1);          // round-to-nearest-even
    return (short)(u >> 16);
}
static __device__ __forceinline__ short f2bfr(float f) {   // cheap round (2 ops)
    unsigned u = __builtin_bit_cast(unsigned, f);
    return (short)((u + 0x8000u) >> 16);
}
static __device__ __forceinline__ float b2f(short s) {
    unsigned u = ((unsigned)(unsigned short)s) << 16;
    return __builtin_bit_cast(float, u);
}

// ---------------- fused fp32->bf16 conversion + weight/bias packing -------------
__global__ __launch_bounds__(256) void cvt_kernel(
    const float* __restrict__ x, const float* __restrict__ pos,
    const float* __restrict__ Wq, const float* __restrict__ Wk, const float* __restrict__ Wv,
    const float* __restrict__ Wpos, const float* __restrict__ Wout,
    const float* __restrict__ bq, const float* __restrict__ bk, const float* __restrict__ bv,
    short* __restrict__ xb, short* __restrict__ posb, short* __restrict__ wqkv,
    short* __restrict__ wpb, short* __restrict__ wob, float* __restrict__ bqkv)
{
    const int blk = blockIdx.x;
    const float* src; short* dst; int off;
    if      (blk < 2048) { src = x;    dst = xb;          off = blk * 2048; }
    else if (blk < 2560) { src = pos;  dst = posb;        off = (blk - 2048) * 2048; }
    else if (blk < 2688) { src = Wq;   dst = wqkv;        off = (blk - 2560) * 2048; }
    else if (blk < 2816) { src = Wk;   dst = wqkv + 262144; off = (blk - 2688) * 2048; }
    else if (blk < 2944) { src = Wv;   dst = wqkv + 524288; off = (blk - 2816) * 2048; }
    else if (blk < 3072) { src = Wpos; dst = wpb;         off = (blk - 2944) * 2048; }
    else if (blk < 3200) { src = Wout; dst = wob;         off = (blk - 3072) * 2048; }
    else {
        int t = threadIdx.x;
        bqkv[t]        = bq[t];        bqkv[256 + t]  = bq[256 + t];
        bqkv[512 + t]  = bk[t];        bqkv[768 + t]  = bk[256 + t];
        bqkv[1024 + t] = bv[t];        bqkv[1280 + t] = bv[256 + t];
        return;
    }
    int i = off + threadIdx.x * 8;
    f4 a = *(const f4*)(src + i);
    f4 b = *(const f4*)(src + i + 4);
    bf16x8 o;
#pragma unroll
    for (int j = 0; j < 4; ++j) { o[j] = f2bf(a[j]); o[4 + j] = f2bf(b[j]); }
    *(bf16x8*)(dst + i) = o;
}

// ---------------- bf16 MFMA GEMM tile: C[128,128] = A@B^T + bias ---------------
template<int OUT_BF16>
static __device__ __forceinline__ void gemm_tile(
    short* As, short* Bs,
    const short* __restrict__ A, const short* __restrict__ B,
    const float* __restrict__ bias, void* __restrict__ Cv,
    int N, int K, int row0, int col0)
{
    const int tid = threadIdx.x, lane = tid & 63, wave = tid >> 6;
    const int col = lane & 15, quad = lane >> 4;
    const int wm = (wave >> 1) * 64, wn = (wave & 1) * 64;
    const int rl = lane & 15;

    const short* Abase = A + (size_t)(row0 + wave * 32 + rl) * K + (lane >> 4) * 8;
    const short* Bbase = B + (size_t)(col0 + wave * 32 + rl) * K + (lane >> 4) * 8;

    f32x4 acc[4][4];
#pragma unroll
    for (int i = 0; i < 4; ++i)
#pragma unroll
        for (int j = 0; j < 4; ++j) acc[i][j] = (f32x4){0.f, 0.f, 0.f, 0.f};

    for (int k0 = 0; k0 < K; k0 += 64) {
        __syncthreads();
#pragma unroll
        for (int c = 0; c < 2; ++c)
#pragma unroll
            for (int hf = 0; hf < 2; ++hf) {
                __builtin_amdgcn_global_load_lds((gptr_t)(Abase + (size_t)(16 * c) * K + k0 + hf * 32),
                                                 (lptr_t)(As + wave * 2048 + c * 1024 + hf * 512), 16, 0, 0);
                __builtin_amdgcn_global_load_lds((gptr_t)(Bbase + (size_t)(16 * c) * K + k0 + hf * 32),
                                                 (lptr_t)(Bs + wave * 2048 + c * 1024 + hf * 512), 16, 0, 0);
            }
        __syncthreads();
#pragma unroll
        for (int kt = 0; kt < 2; ++kt) {
            bf16x8 af[4], bfr[4];
#pragma unroll
            for (int mt = 0; mt < 4; ++mt)
                af[mt] = *(const bf16x8*)&As[((wm >> 4) + mt) * 1024 + (kt * 4 + quad) * 128 + col * 8];
#pragma unroll
            for (int nt = 0; nt < 4; ++nt)
                bfr[nt] = *(const bf16x8*)&Bs[((wn >> 4) + nt) * 1024 + (kt * 4 + quad) * 128 + col * 8];
#pragma unroll
            for (int mt = 0; mt < 4; ++mt)
#pragma unroll
                for (int nt = 0; nt < 4; ++nt)
                    acc[mt][nt] = __builtin_amdgcn_mfma_f32_16x16x32_bf16(af[mt], bfr[nt], acc[mt][nt], 0, 0, 0);
        }
    }

    float bv4[4];
#pragma unroll
    for (int nt = 0; nt < 4; ++nt)
        bv4[nt] = bias ? bias[col0 + wn + nt * 16 + col] : 0.f;
#pragma unroll
    for (int mt = 0; mt < 4; ++mt)
#pragma unroll
        for (int reg = 0; reg < 4; ++reg) {
            int r = row0 + wm + mt * 16 + quad * 4 + reg;
#pragma unroll
            for (int nt = 0; nt < 4; ++nt) {
                int c = col0 + wn + nt * 16 + col;
                float v = acc[mt][nt][reg] + bv4[nt];
                if (OUT_BF16) ((short*)Cv)[(size_t)r * N + c] = f2bf(v);
                else          ((float*)Cv)[(size_t)r * N + c] = v;
            }
        }
}

// QKV (768 tiles, XCD-swizzled) + pos (64 tiles) in one dispatch
__global__ __launch_bounds__(256) void gemm_qkv_pos(
    const short* __restrict__ xb, const short* __restrict__ wqkv,
    const float* __restrict__ bqkv, short* __restrict__ QKV,
    const short* __restrict__ posb, const short* __restrict__ wpb,
    short* __restrict__ Pm)
{
    __shared__ short As[8192], Bs[8192];
    const int bid = blockIdx.x;
    if (bid < 768) {
        // pin each row-panel set to one XCD: xcd covers rows [xcd*8, xcd*8+8)
        const int xcd = bid & 7, s = bid >> 3;
        const int row = xcd * 8 + (s & 7), colt = s >> 3;   // row 0..63, colt 0..11
        gemm_tile<1>(As, Bs, xb, wqkv, bqkv, QKV, 1536, 512, row * 128, colt * 128);
    } else {
        const int t = bid - 768;
        gemm_tile<1>(As, Bs, posb, wpb, nullptr, Pm, 512, 512, (t / 4) * 128, (t % 4) * 128);
    }
}

__global__ __launch_bounds__(256) void gemm_out_kernel(
    const short* __restrict__ A, const short* __restrict__ B,
    const float* __restrict__ bias, float* __restrict__ C)
{
    __shared__ short As[8192], Bs[8192];
    const int bid = blockIdx.x;
    const int xcd = bid & 7, s = bid >> 3;
    const int row = xcd * 8 + (s & 7), colt = s >> 3;       // row 0..63, colt 0..3
    gemm_tile<0>(As, Bs, A, B, bias, C, 512, 512, row * 128, colt * 128);
}

// ---------------- fused: KP = K+P, cb = (log2e/8)*(u.k+vb.p), Vt transpose -----
__global__ __launch_bounds__(256) void kvprep_kernel(
    const short* __restrict__ qkv, const short* __restrict__ pm,
    const float* __restrict__ u, const float* __restrict__ vb,
    short* __restrict__ kp, short* __restrict__ vt, float* __restrict__ cb)
{
    __shared__ short tile[64][72];
    const int tid = threadIdx.x, lr = tid >> 2, lc = (tid & 3) * 16;
    const int bh = blockIdx.y, b = bh >> 3, h = bh & 7, s0 = blockIdx.x * 64;

    const short* kptr = qkv + (size_t)(b * T_SEQ + s0 + lr) * 1536 + 512 + h * DK + lc;
    const short* pptr = pm + (size_t)(s0 + lr) * NFEAT + h * DK + lc;
    const short* vptr = qkv + (size_t)(b * T_SEQ + s0 + lr) * 1536 + 1024 + h * DK + lc;
    bf16x8 k0_ = *(const bf16x8*)kptr,       k1_ = *(const bf16x8*)(kptr + 8);
    bf16x8 p0_ = *(const bf16x8*)pptr,       p1_ = *(const bf16x8*)(pptr + 8);
    bf16x8 v0_ = *(const bf16x8*)vptr,       v1_ = *(const bf16x8*)(vptr + 8);

    float c = 0.f;
    bf16x8 o0, o1;
#pragma unroll
    for (int j = 0; j < 8; ++j) {
        float kf = b2f(k0_[j]), pf = b2f(p0_[j]);
        o0[j] = f2bf(kf + pf);
        c += u[h * DK + lc + j] * kf + vb[h * DK + lc + j] * pf;
        float kf1 = b2f(k1_[j]), pf1 = b2f(p1_[j]);
        o1[j] = f2bf(kf1 + pf1);
        c += u[h * DK + lc + 8 + j] * kf1 + vb[h * DK + lc + 8 + j] * pf1;
    }
    short* kpd = kp + ((size_t)bh * T_SEQ + s0 + lr) * DK + lc;
    *(bf16x8*)kpd       = o0;
    *(bf16x8*)(kpd + 8) = o1;
    c += __shfl_xor(c, 1);
    c += __shfl_xor(c, 2);
    if ((tid & 3) == 0) cb[(size_t)bh * T_SEQ + s0 + lr] = LOG2E_8 * c;

    *(bf16x8*)&tile[lr][lc]     = v0_;
    *(bf16x8*)&tile[lr][lc + 8] = v1_;
    __syncthreads();
    short* dst = vt + (size_t)(bh * DK + lr) * T_SEQ + s0 + lc;
    bf16x8 t0_, t1_;
#pragma unroll
    for (int j = 0; j < 8; ++j) { t0_[j] = tile[lc + j][lr]; t1_[j] = tile[lc + 8 + j][lr]; }
    *(bf16x8*)dst       = t0_;
    *(bf16x8*)(dst + 8) = t1_;
}

// ---------------- flash attention: 128 Q-rows/block, 8 waves, bf16 MFMA --------
// XCD-swizzled grid (flat 512): all 16 t-tiles of a bh pinned to one XCD.
// Register-pipelined KP/Vt/cb staging; Q frags hoisted; exp2-based softmax.
__global__ __launch_bounds__(512) void attn_kernel(
    const short* __restrict__ qkv, const short* __restrict__ kp,
    const short* __restrict__ vt, const float* __restrict__ cb,
    short* __restrict__ attO)
{
    __shared__ __align__(16) short Qs[128][72], KPs[64][72], Vts[64][72], Ps[8][16][72];
    __shared__ float cs[64];
    const int tid = threadIdx.x, lane = tid & 63, wave = tid >> 6;
    const int col = lane & 15, quad = lane >> 4;
    const int idx = blockIdx.x;
    const int xcd = idx & 7, slot = idx >> 3;
    const int bh = (slot >> 4) * 8 + xcd;         // 4 bh per XCD -> 2MB KV in L2
    const int t0 = (slot & 15) * 128;
    const int b = bh >> 3, h = bh & 7;

    {   // Q: 128 rows, 512 threads x 16 shorts
        const int lr = tid >> 2, lc = (tid & 3) * 16;
        const short* qp = qkv + (size_t)(b * T_SEQ + t0 + lr) * 1536 + h * DK + lc;
        *(bf16x8*)&Qs[lr][lc]     = *(const bf16x8*)qp;
        *(bf16x8*)&Qs[lr][lc + 8] = *(const bf16x8*)(qp + 8);
    }
    const int lr8 = tid >> 3, lc8 = (tid & 7) * 8;   // 64x64 staging, 8 shorts/thread

    // prime the register pipeline (s0 = 0)
    bf16x8 kpr = *(const bf16x8*)(kp + ((size_t)bh * T_SEQ + lr8) * DK + lc8);
    bf16x8 vtr = *(const bf16x8*)(vt + ((size_t)(bh * DK + lr8)) * T_SEQ + lc8);
    float cbr = (tid < 64) ? cb[(size_t)bh * T_SEQ + tid] : 0.f;

    __syncthreads();                     // Qs visible
    bf16x8 qa0 = *(const bf16x8*)&Qs[wave * 16 + col][quad * 8];
    bf16x8 qa1 = *(const bf16x8*)&Qs[wave * 16 + col][32 + quad * 8];

    f32x4 Oacc[4];
    float lsum[4] = {0.f, 0.f, 0.f, 0.f};
#pragma unroll
    for (int i = 0; i < 4; ++i) Oacc[i] = (f32x4){0.f, 0.f, 0.f, 0.f};

    for (int s0 = 0; s0 < T_SEQ; s0 += 64) {
        __syncthreads();                 // prev iter's KPs/Vts reads done
        *(bf16x8*)&KPs[lr8][lc8] = kpr;
        *(bf16x8*)&Vts[lr8][lc8] = vtr;
        if (tid < 64) cs[tid] = cbr;
        __syncthreads();

        // prefetch next tile (wraps harmlessly on last iter)
        const int sn = (s0 + 64) & (T_SEQ - 1);
        kpr = *(const bf16x8*)(kp + ((size_t)bh * T_SEQ + sn + lr8) * DK + lc8);
        vtr = *(const bf16x8*)(vt + ((size_t)(bh * DK + lr8)) * T_SEQ + sn + lc8);
        if (tid < 64) cbr = cb[(size_t)bh * T_SEQ + sn + tid];

        f32x4 S[4];
#pragma unroll
        for (int nt = 0; nt < 4; ++nt) S[nt] = (f32x4){0.f, 0.f, 0.f, 0.f};
#pragma unroll
        for (int nt = 0; nt < 4; ++nt) {
            bf16x8 b0 = *(const bf16x8*)&KPs[nt * 16 + col][quad * 8];
            S[nt] = __builtin_amdgcn_mfma_f32_16x16x32_bf16(qa0, b0, S[nt], 0, 0, 0);
            bf16x8 b1 = *(const bf16x8*)&KPs[nt * 16 + col][32 + quad * 8];
            S[nt] = __builtin_amdgcn_mfma_f32_16x16x32_bf16(qa1, b1, S[nt], 0, 0, 0);
        }
        const float c0 = cs[col], c1 = cs[16 + col], c2 = cs[32 + col], c3 = cs[48 + col];
#pragma unroll
        for (int reg = 0; reg < 4; ++reg) {
            int r = quad * 4 + reg;
            float e0 = __builtin_amdgcn_exp2f(fmaf(S[0][reg], LOG2E_8, c0));
            float e1 = __builtin_amdgcn_exp2f(fmaf(S[1][reg], LOG2E_8, c1));
            float e2 = __builtin_amdgcn_exp2f(fmaf(S[2][reg], LOG2E_8, c2));
            float e3 = __builtin_amdgcn_exp2f(fmaf(S[3][reg], LOG2E_8, c3));
            lsum[reg] += (e0 + e1) + (e2 + e3);
            Ps[wave][r][col]      = f2bfr(e0);
            Ps[wave][r][16 + col] = f2bfr(e1);
            Ps[wave][r][32 + col] = f2bfr(e2);
            Ps[wave][r][48 + col] = f2bfr(e3);
        }
        // NO barrier: Ps is strictly per-wave (wave-ordered LDS), Vts guarded above
#pragma unroll
        for (int kt = 0; kt < 2; ++kt) {
            bf16x8 pa = *(const bf16x8*)&Ps[wave][col][kt * 32 + quad * 8];
#pragma unroll
            for (int dt = 0; dt < 4; ++dt) {
                bf16x8 vb = *(const bf16x8*)&Vts[dt * 16 + col][kt * 32 + quad * 8];
                Oacc[dt] = __builtin_amdgcn_mfma_f32_16x16x32_bf16(pa, vb, Oacc[dt], 0, 0, 0);
            }
        }
    }
#pragma unroll
    for (int reg = 0; reg < 4; ++reg) {
        float l = lsum[reg];
#pragma unroll
        for (int off = 1; off < 16; off <<= 1) l += __shfl_xor(l, off);
        float inv = 1.f / l;
        int t = t0 + wave * 16 + quad * 4 + reg;
        short* op = attO + (size_t)(b * T_SEQ + t) * NFEAT + h * DK;
#pragma unroll
        for (int dt = 0; dt < 4; ++dt)
            op[dt * 16 + col] = f2bf(Oacc[dt][reg] * inv);
    }
}

extern "C" void kernel_launch(void* const* d_in, const int* in_sizes, int n_in,
                              void* d_out, int out_size, void* d_ws, size_t ws_size,
                              hipStream_t stream)
{
    const float* x    = (const float*)d_in[0];
    const float* pos  = (const float*)d_in[1];
    const float* Wq   = (const float*)d_in[2];
    const float* bq   = (const float*)d_in[3];
    const float* Wk   = (const float*)d_in[4];
    const float* bk   = (const float*)d_in[5];
    const float* Wv   = (const float*)d_in[6];
    const float* bv   = (const float*)d_in[7];
    const float* Wpos = (const float*)d_in[8];
    const float* Wout = (const float*)d_in[9];
    const float* bout = (const float*)d_in[10];
    const float* pbu  = (const float*)d_in[11];
    const float* pbv  = (const float*)d_in[12];
    float* out = (float*)d_out;

    short* xb   = (short*)d_ws;            // 4,194,304
    short* posb = xb   + 4194304;          // 1,048,576
    short* wqkv = posb + 1048576;          //   786,432
    short* wpb  = wqkv + 786432;           //   262,144
    short* wob  = wpb  + 262144;           //   262,144
    short* QKV  = wob  + 262144;           // 12,582,912  [8192][1536] (Q|K|V)
    short* Pm   = QKV  + 12582912;         // 1,048,576   [2048][512]
    short* KP   = Pm   + 1048576;          // 4,194,304   [bh][s][64]
    short* Vt   = KP   + 4194304;          // 4,194,304   [bh][d][t]
    short* AttO = Vt   + 4194304;          // 4,194,304   [8192][512]
    float* bqkv = (float*)(AttO + 4194304);
    float* Cb   = bqkv + 1536;             // 65,536

    cvt_kernel<<<dim3(3201), dim3(256), 0, stream>>>(x, pos, Wq, Wk, Wv, Wpos, Wout, bq, bk, bv,
                                                     xb, posb, wqkv, wpb, wob, bqkv);
    gemm_qkv_pos<<<dim3(832), dim3(256), 0, stream>>>(xb, wqkv, bqkv, QKV, posb, wpb, Pm);
    kvprep_kernel<<<dim3(T_SEQ / 64, BATCH * NHEAD), dim3(256), 0, stream>>>(QKV, Pm, pbu, pbv, KP, Vt, Cb);
    attn_kernel<<<dim3(512), dim3(512), 0, stream>>>(QKV, KP, Vt, Cb, AttO);
    gemm_out_kernel<<<dim3(256), dim3(256), 0, stream>>>(AttO, wob, bout, out);
}